// Round 1
// baseline (735.043 us; speedup 1.0000x reference)
//
#include <hip/hip_runtime.h>

// LS2T iterated-sums (ORDER=3): B=64, T=4096, D=128, F=64, C=6.
// Y1 = sum_t m0;  Y2 = sum_t m2*cumx(m1);  Y3 = sum_t m5*cumx(m4*cumx(m3))
// where m_c(t) = seq[b,t,:]·kernel[c,:,f] + bias[c,f], cumx = exclusive cumsum.
//
// Decomposition: time chunked into NCHUNK chunks; per-chunk 10-float state per
// (b,f) with associative merge; kernel2 folds chunks sequentially.

#define NC 6
#define B_ 64
#define T_ 4096
#define D_ 128
#define F_ 64
#define TC 64
#define NCHUNK (T_ / TC)
#define NS 10

union SMemU {
    struct {
        float seq[TC][D_ + 4];   // padded for float4 alignment + bank spread
        float k[D_][F_];
    } a;
    float m[NC][TC][F_];         // 98.3 KB, reused after GEMM phase
};

__global__ __launch_bounds__(256, 1)
void ls2t_chunk_kernel(const float* __restrict__ seq,
                       const float* __restrict__ kern,
                       const float* __restrict__ bias,
                       float* __restrict__ ws)
{
    __shared__ SMemU sm;
    const int chunk = blockIdx.x;
    const int b     = blockIdx.y;
    const int tid   = threadIdx.x;
    const int tf = tid & 15;      // f-tile index
    const int tg = tid >> 4;      // t-tile index
    const int f0 = tf * 4;
    const int t0 = tg * 4;

    // ---- stage seq chunk [TC][D_] into LDS (coalesced float4) ----
    {
        const float4* sp = reinterpret_cast<const float4*>(
            seq + ((size_t)b * T_ + (size_t)chunk * TC) * D_);
        #pragma unroll
        for (int it = 0; it < (TC * D_ / 4) / 256; ++it) {
            int i   = it * 256 + tid;
            int row = i >> 5;     // 32 float4 per row
            int c4  = i & 31;
            float4 v = sp[row * 32 + c4];
            *reinterpret_cast<float4*>(&sm.a.seq[row][c4 * 4]) = v;
        }
    }

    float acc[NC][4][4];

    #pragma unroll
    for (int c = 0; c < NC; ++c) {
        __syncthreads();   // prev c's GEMM reads done (and seq staged for c=0)
        // ---- stage kernel[c] [D_][F_] into LDS ----
        {
            const float4* kp = reinterpret_cast<const float4*>(kern + (size_t)c * D_ * F_);
            float4* kd = reinterpret_cast<float4*>(&sm.a.k[0][0]);
            #pragma unroll
            for (int it = 0; it < (D_ * F_ / 4) / 256; ++it)
                kd[it * 256 + tid] = kp[it * 256 + tid];
        }
        __syncthreads();

        float r00=0.f,r01=0.f,r02=0.f,r03=0.f;
        float r10=0.f,r11=0.f,r12=0.f,r13=0.f;
        float r20=0.f,r21=0.f,r22=0.f,r23=0.f;
        float r30=0.f,r31=0.f,r32=0.f,r33=0.f;

        #pragma unroll 8
        for (int d = 0; d < D_; ++d) {
            float4 kv = *reinterpret_cast<const float4*>(&sm.a.k[d][f0]);
            float s0 = sm.a.seq[t0 + 0][d];
            float s1 = sm.a.seq[t0 + 1][d];
            float s2 = sm.a.seq[t0 + 2][d];
            float s3 = sm.a.seq[t0 + 3][d];
            r00 += s0 * kv.x; r01 += s0 * kv.y; r02 += s0 * kv.z; r03 += s0 * kv.w;
            r10 += s1 * kv.x; r11 += s1 * kv.y; r12 += s1 * kv.z; r13 += s1 * kv.w;
            r20 += s2 * kv.x; r21 += s2 * kv.y; r22 += s2 * kv.z; r23 += s2 * kv.w;
            r30 += s3 * kv.x; r31 += s3 * kv.y; r32 += s3 * kv.z; r33 += s3 * kv.w;
        }
        const float4 bv = *reinterpret_cast<const float4*>(&bias[c * F_ + f0]);
        acc[c][0][0]=r00+bv.x; acc[c][0][1]=r01+bv.y; acc[c][0][2]=r02+bv.z; acc[c][0][3]=r03+bv.w;
        acc[c][1][0]=r10+bv.x; acc[c][1][1]=r11+bv.y; acc[c][1][2]=r12+bv.z; acc[c][1][3]=r13+bv.w;
        acc[c][2][0]=r20+bv.x; acc[c][2][1]=r21+bv.y; acc[c][2][2]=r22+bv.z; acc[c][2][3]=r23+bv.w;
        acc[c][3][0]=r30+bv.x; acc[c][3][1]=r31+bv.y; acc[c][3][2]=r32+bv.z; acc[c][3][3]=r33+bv.w;
    }

    __syncthreads();   // all GEMM reads of sm.a done; safe to overwrite with sm.m
    #pragma unroll
    for (int c = 0; c < NC; ++c)
        #pragma unroll
        for (int i = 0; i < 4; ++i)
            *reinterpret_cast<float4*>(&sm.m[c][t0 + i][f0]) =
                make_float4(acc[c][i][0], acc[c][i][1], acc[c][i][2], acc[c][i][3]);
    __syncthreads();

    // ---- sequential in-chunk scan: one thread per f ----
    if (tid < F_) {
        const int f = tid;
        float a0=0.f, s1=0.f, s2=0.f, q2=0.f;
        float su=0.f, sv=0.f, sw=0.f, qvu=0.f, qwv=0.f, qwvu=0.f;
        for (int t = 0; t < TC; ++t) {
            float m0 = sm.m[0][t][f];
            float m1 = sm.m[1][t][f];
            float m2 = sm.m[2][t][f];
            float m3 = sm.m[3][t][f];
            float m4 = sm.m[4][t][f];
            float m5 = sm.m[5][t][f];
            a0   += m0;
            q2   += m2 * s1;      // s1 is exclusive cumsum of m1
            s2   += m2;
            s1   += m1;
            qwvu += m5 * qvu;     // qvu is exclusive cum of m4*cumx(m3)
            qwv  += m5 * sv;
            sw   += m5;
            qvu  += m4 * su;      // su is exclusive cumsum of m3
            sv   += m4;
            su   += m3;
        }
        float st[NS] = {a0, s1, s2, q2, su, sv, sw, qvu, qwv, qwvu};
        float* wp = ws + (((size_t)b * NCHUNK + chunk) * F_ + f) * NS;
        #pragma unroll
        for (int s = 0; s < NS; ++s) wp[s] = st[s];
    }
}

__global__ __launch_bounds__(64)
void ls2t_merge_kernel(const float* __restrict__ ws, float* __restrict__ out)
{
    const int b = blockIdx.x;
    const int f = threadIdx.x;
    float A[NS];
    #pragma unroll
    for (int s = 0; s < NS; ++s) A[s] = 0.f;

    for (int ch = 0; ch < NCHUNK; ++ch) {
        const float* rp = ws + (((size_t)b * NCHUNK + ch) * F_ + f) * NS;
        float r[NS];
        #pragma unroll
        for (int s = 0; s < NS; ++s) r[s] = rp[s];
        // merge A (left) with r (right)
        float a0   = A[0] + r[0];
        float q2   = A[3] + r[3] + A[1] * r[2];
        float s1   = A[1] + r[1];
        float s2   = A[2] + r[2];
        float qwvu = A[9] + r[9] + A[7] * r[6] + A[4] * r[8];
        float qwv  = A[8] + r[8] + A[5] * r[6];
        float qvu  = A[7] + r[7] + A[4] * r[5];
        float su   = A[4] + r[4];
        float sv   = A[5] + r[5];
        float sw   = A[6] + r[6];
        A[0]=a0; A[1]=s1; A[2]=s2; A[3]=q2; A[4]=su;
        A[5]=sv; A[6]=sw; A[7]=qvu; A[8]=qwv; A[9]=qwvu;
    }
    // out[b, f, 0..2] = Y1, Y2, Y3
    float* op = out + ((size_t)b * F_ + f) * 3;
    op[0] = A[0];
    op[1] = A[3];
    op[2] = A[9];
}

extern "C" void kernel_launch(void* const* d_in, const int* in_sizes, int n_in,
                              void* d_out, int out_size, void* d_ws, size_t ws_size,
                              hipStream_t stream) {
    const float* seq  = (const float*)d_in[0];
    const float* kern = (const float*)d_in[1];
    const float* bias = (const float*)d_in[2];
    float* out = (float*)d_out;
    float* ws  = (float*)d_ws;   // needs B_*NCHUNK*F_*NS*4 = 10.5 MB

    dim3 g1(NCHUNK, B_);
    ls2t_chunk_kernel<<<g1, 256, 0, stream>>>(seq, kern, bias, ws);
    ls2t_merge_kernel<<<B_, 64, 0, stream>>>(ws, out);
}

// Round 2
// 64.791 us; speedup vs baseline: 11.3448x; 11.3448x over previous
//
#include <hip/hip_runtime.h>

// LS2T iterated sums (ORDER=3): B=64, T=4096, D=128, F=64, C=6.
// m_c(t,f) = seq[b,t,:]·kernel[c,:,f] + bias[c,f]
// Y1 = sum m0; Y2 = sum m2*cumx(m1); Y3 = sum m5*cumx(m4*cumx(m3))
//
// Round 2: bf16 MFMA GEMM (16x16x32), scan fully in registers via
// shfl-butterfly merge of the 10-float associative state. LDS: kernel
// staged once per block (96KB bf16, f-major, XOR-swizzled), seq chunk
// double-buffered (2x16KB, XOR-swizzled). 8 chunks folded per block.

#define NC 6
#define B_ 64
#define T_ 4096
#define D_ 128
#define F_ 64
#define TC 64
#define G_ 8
#define NCHUNK (T_ / TC)    // 64
#define NGRP (NCHUNK / G_)  // 8

typedef __attribute__((ext_vector_type(8))) short short8v;
typedef __attribute__((ext_vector_type(4))) float f32x4;
typedef __attribute__((ext_vector_type(4))) unsigned short ushort4v;
typedef __attribute__((ext_vector_type(8))) unsigned short ushort8v;

__device__ __forceinline__ unsigned short f2bf(float x) {
    unsigned u = __float_as_uint(x);
    unsigned r = u + 0x7FFFu + ((u >> 16) & 1u);   // RNE
    return (unsigned short)(r >> 16);
}

struct St { float a0, s1, s2, q2, su, sv, sw, qvu, qwv, qwvu; };

__device__ __forceinline__ St mergeSt(const St& A, const St& B) {
    St r;
    r.a0   = A.a0 + B.a0;
    r.q2   = A.q2 + B.q2 + A.s1 * B.s2;
    r.s1   = A.s1 + B.s1;
    r.s2   = A.s2 + B.s2;
    r.qwvu = A.qwvu + B.qwvu + A.qvu * B.sw + A.su * B.qwv;
    r.qwv  = A.qwv + B.qwv + A.sv * B.sw;
    r.qvu  = A.qvu + B.qvu + A.su * B.sv;
    r.su   = A.su + B.su;
    r.sv   = A.sv + B.sv;
    r.sw   = A.sw + B.sw;
    return r;
}

__device__ __forceinline__ St shflSt(const St& s, int m) {
    St o;
    o.a0 = __shfl_xor(s.a0, m);   o.s1 = __shfl_xor(s.s1, m);
    o.s2 = __shfl_xor(s.s2, m);   o.q2 = __shfl_xor(s.q2, m);
    o.su = __shfl_xor(s.su, m);   o.sv = __shfl_xor(s.sv, m);
    o.sw = __shfl_xor(s.sw, m);   o.qvu = __shfl_xor(s.qvu, m);
    o.qwv = __shfl_xor(s.qwv, m); o.qwvu = __shfl_xor(s.qwvu, m);
    return o;
}

__device__ __forceinline__ void butterfly(St& s, int m, int lane) {
    St o = shflSt(s, m);
    bool up = (lane & m) != 0;     // upper half holds the LATER segment
    St A = up ? o : s;
    St B = up ? s : o;
    s = mergeSt(A, B);
}

__global__ __launch_bounds__(256, 1)
void ls2t_mfma_kernel(const float* __restrict__ seq,
                      const float* __restrict__ kern,
                      const float* __restrict__ bias,
                      float* __restrict__ ws)
{
    __shared__ unsigned short klds[NC][F_ * D_];  // bf16, [c][f][d], swizzled
    __shared__ unsigned short slds[2][TC * D_];   // bf16, [t][d],   swizzled

    const int tid  = threadIdx.x;
    const int grp  = blockIdx.x;   // chunk group (8 chunks each)
    const int b    = blockIdx.y;
    const int lane = tid & 63;
    const int wv   = tid >> 6;     // wave 0..3 -> f-range
    const int fr   = lane & 15;
    const int lg   = lane >> 4;
    const int f    = wv * 16 + fr;

    // ---- stage kernel: [c][d][f] f32 global -> [c][f][d] bf16 LDS ----
    {
        const int sf = tid & 63;      // f this thread handles
        const int dg = tid >> 6;      // d-group (32 d's each)
        #pragma unroll
        for (int c = 0; c < NC; ++c) {
            const float* kp = kern + ((size_t)c * D_ + dg * 32) * F_ + sf;
            float v[32];
            #pragma unroll
            for (int j = 0; j < 32; ++j) v[j] = kp[(size_t)j * F_];
            #pragma unroll
            for (int q = 0; q < 4; ++q) {
                ushort8v w;
                #pragma unroll
                for (int e = 0; e < 8; ++e) w[e] = f2bf(v[q * 8 + e]);
                int d0  = dg * 32 + q * 8;
                int idx = (sf * D_ + d0) ^ ((sf & 7) << 3);
                *reinterpret_cast<ushort8v*>(&klds[c][idx]) = w;
            }
        }
    }

    // bias per lane (its f), all 6 components
    float bc[NC];
    #pragma unroll
    for (int c = 0; c < NC; ++c) bc[c] = bias[c * F_ + f];

    const float* sbase = seq + (size_t)b * T_ * D_;

    // ---- prologue: stage chunk 0 ----
    float4 v[8];
    {
        const float4* sp = reinterpret_cast<const float4*>(
            sbase + (size_t)(grp * G_) * TC * D_);
        #pragma unroll
        for (int it = 0; it < 8; ++it) v[it] = sp[it * 256 + tid];
    }
    #pragma unroll
    for (int it = 0; it < 8; ++it) {
        int p = it * 256 + tid;
        int t = p >> 5;          // 32 float4 per row
        int dq = p & 31;
        ushort4v w;
        w[0] = f2bf(v[it].x); w[1] = f2bf(v[it].y);
        w[2] = f2bf(v[it].z); w[3] = f2bf(v[it].w);
        int idx = (t * D_ + dq * 4) ^ ((t & 7) << 3);
        *reinterpret_cast<ushort4v*>(&slds[0][idx]) = w;
    }
    __syncthreads();

    St R = {0, 0, 0, 0, 0, 0, 0, 0, 0, 0};

    #pragma unroll 1
    for (int ch = 0; ch < G_; ++ch) {
        const int buf = ch & 1;

        // issue next chunk's global loads early (hide HBM under compute)
        if (ch + 1 < G_) {
            const float4* sp = reinterpret_cast<const float4*>(
                sbase + (size_t)(grp * G_ + ch + 1) * TC * D_);
            #pragma unroll
            for (int it = 0; it < 8; ++it) v[it] = sp[it * 256 + tid];
        }

        // ---- MFMA GEMM: M[6][64t][16f per wave] ----
        f32x4 acc[NC][4];
        #pragma unroll
        for (int c = 0; c < NC; ++c)
            #pragma unroll
            for (int tf = 0; tf < 4; ++tf)
                acc[c][tf] = (f32x4){0.f, 0.f, 0.f, 0.f};

        #pragma unroll
        for (int ks = 0; ks < 4; ++ks) {
            const int d0 = ks * 32 + lg * 8;
            short8v a[4];
            #pragma unroll
            for (int tf = 0; tf < 4; ++tf) {
                int t = tf * 16 + fr;
                a[tf] = *reinterpret_cast<const short8v*>(
                    &slds[buf][(t * D_ + d0) ^ ((t & 7) << 3)]);
            }
            #pragma unroll
            for (int c = 0; c < NC; ++c) {
                short8v bfrag = *reinterpret_cast<const short8v*>(
                    &klds[c][(f * D_ + d0) ^ ((f & 7) << 3)]);
                #pragma unroll
                for (int tf = 0; tf < 4; ++tf)
                    acc[c][tf] = __builtin_amdgcn_mfma_f32_16x16x32_bf16(
                        a[tf], bfrag, acc[c][tf], 0, 0, 0);
            }
        }

        // ---- scan: lane-local 4-t segments -> butterfly -> in-lane fold ----
        // lane holds M[t = tf*16 + lg*4 + r][f] in acc[c][tf][r]
        St S;
        #pragma unroll
        for (int tf = 0; tf < 4; ++tf) {
            St s = {0, 0, 0, 0, 0, 0, 0, 0, 0, 0};
            #pragma unroll
            for (int r = 0; r < 4; ++r) {
                float m0 = acc[0][tf][r] + bc[0];
                float m1 = acc[1][tf][r] + bc[1];
                float m2 = acc[2][tf][r] + bc[2];
                float m3 = acc[3][tf][r] + bc[3];
                float m4 = acc[4][tf][r] + bc[4];
                float m5 = acc[5][tf][r] + bc[5];
                s.a0 += m0;
                s.q2   = fmaf(m2, s.s1, s.q2);   // s1 = exclusive cumsum(m1)
                s.s2  += m2;
                s.s1  += m1;
                s.qwvu = fmaf(m5, s.qvu, s.qwvu);
                s.qwv  = fmaf(m5, s.sv, s.qwv);
                s.sw  += m5;
                s.qvu  = fmaf(m4, s.su, s.qvu);
                s.sv  += m4;
                s.su  += m3;
            }
            butterfly(s, 16, lane);   // merge lane-groups (4-t segs -> 8-t)
            butterfly(s, 32, lane);   // -> full 16-t tfrag state, all lanes
            S = (tf == 0) ? s : mergeSt(S, s);
        }
        R = mergeSt(R, S);

        __syncthreads();   // all reads of slds[buf^1] from prev iter done
        if (ch + 1 < G_) {
            #pragma unroll
            for (int it = 0; it < 8; ++it) {
                int p = it * 256 + tid;
                int t = p >> 5;
                int dq = p & 31;
                ushort4v w;
                w[0] = f2bf(v[it].x); w[1] = f2bf(v[it].y);
                w[2] = f2bf(v[it].z); w[3] = f2bf(v[it].w);
                int idx = (t * D_ + dq * 4) ^ ((t & 7) << 3);
                *reinterpret_cast<ushort4v*>(&slds[buf ^ 1][idx]) = w;
            }
        }
        __syncthreads();
    }

    // one lane-group per f writes the block's folded state
    if (lg == 0) {
        float* wp = ws + (((size_t)b * NGRP + grp) * F_ + f) * 10;
        wp[0] = R.a0;  wp[1] = R.s1;  wp[2] = R.s2;  wp[3] = R.q2;
        wp[4] = R.su;  wp[5] = R.sv;  wp[6] = R.sw;  wp[7] = R.qvu;
        wp[8] = R.qwv; wp[9] = R.qwvu;
    }
}

__global__ __launch_bounds__(64)
void ls2t_fold_kernel(const float* __restrict__ ws, float* __restrict__ out)
{
    const int b = blockIdx.x;
    const int f = threadIdx.x;
    St A = {0, 0, 0, 0, 0, 0, 0, 0, 0, 0};
    #pragma unroll
    for (int g = 0; g < NGRP; ++g) {
        const float* rp = ws + (((size_t)b * NGRP + g) * F_ + f) * 10;
        St r = {rp[0], rp[1], rp[2], rp[3], rp[4],
                rp[5], rp[6], rp[7], rp[8], rp[9]};
        A = mergeSt(A, r);
    }
    float* op = out + ((size_t)b * F_ + f) * 3;
    op[0] = A.a0;
    op[1] = A.q2;
    op[2] = A.qwvu;
}

extern "C" void kernel_launch(void* const* d_in, const int* in_sizes, int n_in,
                              void* d_out, int out_size, void* d_ws, size_t ws_size,
                              hipStream_t stream) {
    const float* seq  = (const float*)d_in[0];
    const float* kern = (const float*)d_in[1];
    const float* bias = (const float*)d_in[2];
    float* out = (float*)d_out;
    float* ws  = (float*)d_ws;   // B_*NGRP*F_*10*4 = 1.31 MB

    dim3 g1(NGRP, B_);           // 512 blocks
    ls2t_mfma_kernel<<<g1, 256, 0, stream>>>(seq, kern, bias, ws);
    ls2t_fold_kernel<<<B_, F_, 0, stream>>>(ws, out);
}

// Round 3
// 62.024 us; speedup vs baseline: 11.8509x; 1.0446x over previous
//
#include <hip/hip_runtime.h>

// LS2T iterated sums (ORDER=3): B=64, T=4096, D=128, F=64, C=6.
// m_c(t,f) = seq[b,t,:]·kernel[c,:,f] + bias[c,f]
// Y1 = sum m0; Y2 = sum m2*cumx(m1); Y3 = sum m5*cumx(m4*cumx(m3))
//
// Round 3: 512 thr (8 waves = 2 time-groups x 4 f-waves), 1 block/CU.
// Contiguous-per-lane t-remap: lane-group lg owns t-stripe [lg*128,+128) of
// its wave-group's 512-t half -> scan state chains in-lane across all 8
// iterations, butterfly only once at the end. Bias folded into MFMA acc init.

#define NC 6
#define B_ 64
#define T_ 4096
#define D_ 128
#define F_ 64
#define NGRP 4      // blocks per batch; each owns 1024 t
#define NITER 8
#define TPB 512
#define NSEG (NGRP * 2)   // 8 time-segments per (b,f) in ws

typedef __attribute__((ext_vector_type(8))) short short8v;
typedef __attribute__((ext_vector_type(4))) float f32x4;
typedef __attribute__((ext_vector_type(4))) unsigned short ushort4v;
typedef __attribute__((ext_vector_type(8))) unsigned short ushort8v;

__device__ __forceinline__ unsigned short f2bf(float x) {
    unsigned u = __float_as_uint(x);
    unsigned r = u + 0x7FFFu + ((u >> 16) & 1u);   // RNE
    return (unsigned short)(r >> 16);
}

__device__ __forceinline__ int swzs(int vrow) {    // slds swizzle key (4 bits)
    return (vrow & 3) | (((vrow >> 4) & 3) << 2);
}

struct St { float a0, s1, s2, q2, su, sv, sw, qvu, qwv, qwvu; };

__device__ __forceinline__ St mergeSt(const St& A, const St& B) {
    St r;
    r.a0   = A.a0 + B.a0;
    r.q2   = A.q2 + B.q2 + A.s1 * B.s2;
    r.s1   = A.s1 + B.s1;
    r.s2   = A.s2 + B.s2;
    r.qwvu = A.qwvu + B.qwvu + A.qvu * B.sw + A.su * B.qwv;
    r.qwv  = A.qwv + B.qwv + A.sv * B.sw;
    r.qvu  = A.qvu + B.qvu + A.su * B.sv;
    r.su   = A.su + B.su;
    r.sv   = A.sv + B.sv;
    r.sw   = A.sw + B.sw;
    return r;
}

__device__ __forceinline__ St shflSt(const St& s, int m) {
    St o;
    o.a0 = __shfl_xor(s.a0, m);   o.s1 = __shfl_xor(s.s1, m);
    o.s2 = __shfl_xor(s.s2, m);   o.q2 = __shfl_xor(s.q2, m);
    o.su = __shfl_xor(s.su, m);   o.sv = __shfl_xor(s.sv, m);
    o.sw = __shfl_xor(s.sw, m);   o.qvu = __shfl_xor(s.qvu, m);
    o.qwv = __shfl_xor(s.qwv, m); o.qwvu = __shfl_xor(s.qwvu, m);
    return o;
}

__device__ __forceinline__ void butterfly(St& s, int m, int lane) {
    St o = shflSt(s, m);
    bool up = (lane & m) != 0;     // upper half holds the LATER segment
    St A = up ? o : s;
    St B = up ? s : o;
    s = mergeSt(A, B);
}

__global__ __launch_bounds__(TPB, 2)
void ls2t_kernel(const float* __restrict__ seq,
                 const float* __restrict__ kern,
                 const float* __restrict__ bias,
                 float* __restrict__ ws)
{
    __shared__ unsigned short klds[NC][F_ * D_];   // 96 KB, [c][f][d] swizzled
    __shared__ unsigned short slds[2][64 * D_];    // 2 x 16 KB, per wave-group

    const int tid  = threadIdx.x;
    const int grp  = blockIdx.x;
    const int b    = blockIdx.y;
    const int lane = tid & 63;
    const int w    = tid >> 6;
    const int wg   = w >> 2;       // time-half of this wave
    const int wv   = w & 3;        // f-range of this wave
    const int fr   = lane & 15;
    const int lg   = lane >> 4;
    const int f    = wv * 16 + fr;

    // ---- stage kernel: [c][d][f] f32 -> klds [c][f][d] bf16 swizzled ----
    {
        const int sf = tid & 63;
        const int dg = tid >> 6;          // 8 groups x 16 d each
        #pragma unroll
        for (int c = 0; c < NC; ++c) {
            const float* kp = kern + ((size_t)c * D_ + dg * 16) * F_ + sf;
            float vv[16];
            #pragma unroll
            for (int j = 0; j < 16; ++j) vv[j] = kp[(size_t)j * F_];
            #pragma unroll
            for (int q = 0; q < 2; ++q) {
                ushort8v w8;
                #pragma unroll
                for (int e = 0; e < 8; ++e) w8[e] = f2bf(vv[q * 8 + e]);
                int idx = (sf * D_ + dg * 16 + q * 8) ^ ((sf & 15) << 3);
                *reinterpret_cast<ushort8v*>(&klds[c][idx]) = w8;
            }
        }
    }

    float bc[NC];
    #pragma unroll
    for (int c = 0; c < NC; ++c) bc[c] = bias[c * F_ + f];

    const float* sbase = seq + ((size_t)b * T_ + (size_t)grp * 1024) * D_;

    // staging map: p = k*TPB+tid; rr = p>>5 (0..127): buffer rr>>6, vrow rr&63
    // t_local(i, rr) = (rr>>6)*512 + ((rr>>4)&3)*128 + i*16 + (rr&15)
    float4 v[8];

    auto issue_loads = [&](int i) {
        #pragma unroll
        for (int k = 0; k < 8; ++k) {
            int p = k * TPB + tid;
            int rr = p >> 5, c4 = p & 31;
            int tl = ((rr >> 6) * 512) + (((rr >> 4) & 3) * 128) + i * 16 + (rr & 15);
            v[k] = *(reinterpret_cast<const float4*>(sbase + (size_t)tl * D_) + c4);
        }
    };
    auto write_lds = [&]() {
        #pragma unroll
        for (int k = 0; k < 8; ++k) {
            int p = k * TPB + tid;
            int rr = p >> 5, c4 = p & 31;
            int wgs = rr >> 6, vrow = rr & 63;
            ushort4v w4;
            w4[0] = f2bf(v[k].x); w4[1] = f2bf(v[k].y);
            w4[2] = f2bf(v[k].z); w4[3] = f2bf(v[k].w);
            int idx = (vrow * D_ + c4 * 4) ^ (swzs(vrow) << 3);
            *reinterpret_cast<ushort4v*>(&slds[wgs][idx]) = w4;
        }
    };

    // prologue: stage iteration 0
    issue_loads(0);
    write_lds();
    __syncthreads();

    St R = {0, 0, 0, 0, 0, 0, 0, 0, 0, 0};

    #pragma unroll 1
    for (int i = 0; i < NITER; ++i) {
        if (i + 1 < NITER) issue_loads(i + 1);   // hide HBM under compute

        // ---- MFMA: M[6][64 vrow][16 f per wave], bias pre-loaded in acc ----
        f32x4 acc[NC][4];
        #pragma unroll
        for (int c = 0; c < NC; ++c)
            #pragma unroll
            for (int tf = 0; tf < 4; ++tf)
                acc[c][tf] = (f32x4){bc[c], bc[c], bc[c], bc[c]};

        #pragma unroll
        for (int ks = 0; ks < 4; ++ks) {
            const int d0 = ks * 32 + lg * 8;
            short8v a[4];
            #pragma unroll
            for (int tf = 0; tf < 4; ++tf) {
                int vrow = (fr >> 2) * 16 + tf * 4 + (fr & 3);
                a[tf] = *reinterpret_cast<const short8v*>(
                    &slds[wg][(vrow * D_ + d0) ^ (swzs(vrow) << 3)]);
            }
            #pragma unroll
            for (int c = 0; c < NC; ++c) {
                short8v bfrag = *reinterpret_cast<const short8v*>(
                    &klds[c][(f * D_ + d0) ^ ((f & 15) << 3)]);
                #pragma unroll
                for (int tf = 0; tf < 4; ++tf)
                    acc[c][tf] = __builtin_amdgcn_mfma_f32_16x16x32_bf16(
                        a[tf], bfrag, acc[c][tf], 0, 0, 0);
            }
        }

        // ---- scan: lane owns contiguous t = wg*512+lg*128+i*16+(tf*4+r) ----
        #pragma unroll
        for (int tf = 0; tf < 4; ++tf) {
            #pragma unroll
            for (int r = 0; r < 4; ++r) {
                float m0 = acc[0][tf][r];
                float m1 = acc[1][tf][r];
                float m2 = acc[2][tf][r];
                float m3 = acc[3][tf][r];
                float m4 = acc[4][tf][r];
                float m5 = acc[5][tf][r];
                R.a0  += m0;
                R.q2   = fmaf(m2, R.s1, R.q2);   // s1 = exclusive cumsum(m1)
                R.s2  += m2;
                R.s1  += m1;
                R.qwvu = fmaf(m5, R.qvu, R.qwvu);
                R.qwv  = fmaf(m5, R.sv, R.qwv);
                R.sw  += m5;
                R.qvu  = fmaf(m4, R.su, R.qvu);
                R.sv  += m4;
                R.su  += m3;
            }
        }

        __syncthreads();                 // all waves done reading slds
        if (i + 1 < NITER) write_lds();  // waits vmcnt, converts, writes
        __syncthreads();
    }

    // merge lane-group stripes (time order: lg 0..3) -> wave-group state
    butterfly(R, 16, lane);
    butterfly(R, 32, lane);

    if (lg == 0) {
        float* wp = ws + ((((size_t)b * NGRP + grp) * 2 + wg) * F_ + f) * 10;
        wp[0] = R.a0;  wp[1] = R.s1;  wp[2] = R.s2;  wp[3] = R.q2;
        wp[4] = R.su;  wp[5] = R.sv;  wp[6] = R.sw;  wp[7] = R.qvu;
        wp[8] = R.qwv; wp[9] = R.qwvu;
    }
}

__global__ __launch_bounds__(64)
void ls2t_fold_kernel(const float* __restrict__ ws, float* __restrict__ out)
{
    const int b = blockIdx.x;
    const int f = threadIdx.x;
    St A = {0, 0, 0, 0, 0, 0, 0, 0, 0, 0};
    #pragma unroll
    for (int g = 0; g < NSEG; ++g) {
        const float* rp = ws + (((size_t)b * NSEG + g) * F_ + f) * 10;
        St r = {rp[0], rp[1], rp[2], rp[3], rp[4],
                rp[5], rp[6], rp[7], rp[8], rp[9]};
        A = mergeSt(A, r);
    }
    float* op = out + ((size_t)b * F_ + f) * 3;
    op[0] = A.a0;
    op[1] = A.q2;
    op[2] = A.qwvu;
}

extern "C" void kernel_launch(void* const* d_in, const int* in_sizes, int n_in,
                              void* d_out, int out_size, void* d_ws, size_t ws_size,
                              hipStream_t stream) {
    const float* seq  = (const float*)d_in[0];
    const float* kern = (const float*)d_in[1];
    const float* bias = (const float*)d_in[2];
    float* out = (float*)d_out;
    float* ws  = (float*)d_ws;   // B_*NSEG*F_*10*4 = 1.31 MB

    dim3 g1(NGRP, B_);           // 256 blocks, 1 per CU
    ls2t_kernel<<<g1, TPB, 0, stream>>>(seq, kern, bias, ws);
    ls2t_fold_kernel<<<B_, F_, 0, stream>>>(ws, out);
}